// Round 1
// baseline (863.933 us; speedup 1.0000x reference)
//
#include <hip/hip_runtime.h>
#include <hip/hip_bf16.h>

#define DIM   4096
#define NHEAD 32
#define NKV   8
#define HD    128
#define BATCH 2
#define SEQ   2048
#define M1    (BATCH*SEQ)           // 4096 rows of x
#define NF    ((NHEAD+2*NKV)*HD)    // 6144 qkv features

typedef __attribute__((ext_vector_type(8))) short short8;
typedef __attribute__((ext_vector_type(4))) short short4v;
typedef __attribute__((ext_vector_type(4))) float f32x4;

__device__ __forceinline__ float bf2f(short s) {
    unsigned u = ((unsigned)(unsigned short)s) << 16;
    return __builtin_bit_cast(float, u);
}
__device__ __forceinline__ short f2bf(float f) {
    unsigned u = __builtin_bit_cast(unsigned, f);
    u = u + 0x7fffu + ((u >> 16) & 1u);   // RNE
    return (short)(u >> 16);
}

__device__ __forceinline__ void gload_lds16(const void* g, void* l) {
    __builtin_amdgcn_global_load_lds(
        (const __attribute__((address_space(1))) void*)g,
        (__attribute__((address_space(3))) void*)l, 16, 0, 0);
}

// ---------------- fp32 -> bf16 convert ----------------
__global__ void f2bf_k(const float* __restrict__ src, short* __restrict__ dst, int n4) {
    int i = blockIdx.x * blockDim.x + threadIdx.x;
    if (i >= n4) return;
    float4 v = ((const float4*)src)[i];
    short4v o;
    o[0] = f2bf(v.x); o[1] = f2bf(v.y); o[2] = f2bf(v.z); o[3] = f2bf(v.w);
    ((short4v*)dst)[i] = o;
}

// ---------------- GEMM  C[M][N] = A[M][K] * Bm[N][K]^T  (m97 structure) ----------------
template<int OUT_BF16>
__global__ __launch_bounds__(256) void gemm_bt(const short* __restrict__ A,
                                               const short* __restrict__ Bm,
                                               void* __restrict__ Cout,
                                               int M, int N, int K) {
    __shared__ __align__(16) short As[128*64];
    __shared__ __align__(16) short Bs[128*64];
    const int nb   = N >> 7;
    const int brow = blockIdx.x / nb, bcol = blockIdx.x % nb;
    const int t    = threadIdx.x;
    const int lane = t & 63, w = t >> 6;
    const int wr = (w >> 1) * 64, wc = (w & 1) * 64;
    const int l16 = lane & 15, lhi = lane >> 4;
    f32x4 acc[4][4] = {};
    const size_t abase = (size_t)(brow * 128) * K;
    const size_t bbase = (size_t)(bcol * 128) * K;
    for (int k0 = 0; k0 < K; k0 += 64) {
#pragma unroll
        for (int i = 0; i < 4; ++i) {
            int e = (i * 256 + t) * 8;
            int r = e >> 6, c = e & 63;
            gload_lds16(A + abase + (size_t)r * K + k0 + c, &As[e]);
        }
#pragma unroll
        for (int i = 0; i < 4; ++i) {
            int e = (i * 256 + t) * 8;
            int r = e >> 6, c = e & 63;
            gload_lds16(Bm + bbase + (size_t)r * K + k0 + c, &Bs[e]);
        }
        __syncthreads();
#pragma unroll
        for (int kk = 0; kk < 2; ++kk) {
            short8 a[4], b[4];
#pragma unroll
            for (int m = 0; m < 4; ++m)
                a[m] = *(const short8*)&As[(wr + m*16 + l16)*64 + kk*32 + lhi*8];
#pragma unroll
            for (int n = 0; n < 4; ++n)
                b[n] = *(const short8*)&Bs[(wc + n*16 + l16)*64 + kk*32 + lhi*8];
#pragma unroll
            for (int m = 0; m < 4; ++m)
#pragma unroll
                for (int n = 0; n < 4; ++n)
                    acc[m][n] = __builtin_amdgcn_mfma_f32_16x16x32_bf16(a[m], b[n], acc[m][n], 0, 0, 0);
        }
        __syncthreads();
    }
#pragma unroll
    for (int m = 0; m < 4; ++m)
#pragma unroll
        for (int n = 0; n < 4; ++n)
#pragma unroll
            for (int r = 0; r < 4; ++r) {
                size_t row = brow*128 + wr + m*16 + lhi*4 + r;
                size_t col = bcol*128 + wc + n*16 + l16;
                if (OUT_BF16)
                    ((short*)Cout)[row * N + col] = f2bf(acc[m][n][r]);
                else
                    ((float*)Cout)[row * N + col] = acc[m][n][r];
            }
}

// ---------------- RoPE + split + V transpose ----------------
// qkv bf16 [M1][NF]; freqs fp32 [SEQ][64][2]
// qb [B][NHEAD][SEQ][HD], kb [B][NKV][SEQ][HD], vtb [B][NKV][HD][SEQ]
__global__ void rope_split_k(const short* __restrict__ qkv,
                             const float* __restrict__ freqs,
                             short* __restrict__ qb, short* __restrict__ kb,
                             short* __restrict__ vtb) {
    int tid  = blockIdx.x * blockDim.x + threadIdx.x;   // one per 8 elems
    int colg = tid % (NF / 8);
    int row  = tid / (NF / 8);
    if (row >= M1) return;
    int b = row >> 11, s = row & 2047;
    int f = colg << 3;
    int h = f >> 7, d = f & 127;
    short8 v = *(const short8*)&qkv[(size_t)row * NF + f];
    if (h < NHEAD + NKV) {
        const float4 fa = *(const float4*)&freqs[(size_t)(s*64 + (d>>1)) * 2];
        const float4 fb = *(const float4*)&freqs[(size_t)(s*64 + (d>>1)) * 2 + 4];
        float fr[8] = {fa.x, fa.y, fa.z, fa.w, fb.x, fb.y, fb.z, fb.w};
        short8 o;
#pragma unroll
        for (int p = 0; p < 4; ++p) {
            float x0 = bf2f(v[2*p]), x1 = bf2f(v[2*p+1]);
            float c = fr[2*p], sn = fr[2*p+1];
            o[2*p]   = f2bf(x0 * c  - x1 * sn);
            o[2*p+1] = f2bf(x0 * sn + x1 * c);
        }
        if (h < NHEAD)
            *(short8*)&qb[((((size_t)b*NHEAD + h)*SEQ + s) << 7) + d] = o;
        else
            *(short8*)&kb[((((size_t)b*NKV + (h - NHEAD))*SEQ + s) << 7) + d] = o;
    } else {
        int kvh = h - NHEAD - NKV;
        size_t base = (((size_t)b*NKV + kvh)*HD + d)*SEQ + s;
#pragma unroll
        for (int j = 0; j < 8; ++j)
            vtb[base + (size_t)j * SEQ] = v[j];
    }
}

// ---------------- flash attention ----------------
// swizzled LDS addressing: chunk ^= (row&7); staged with inverse-permuted GLOBAL src
__device__ __forceinline__ int swzK(int row, int chunk) {  // Ks row=256B, 16 chunks
    return row*128 + ((chunk ^ (row & 7)) << 3);
}
__device__ __forceinline__ int swzV(int row, int chunk) {  // Vs row=128B, 8 chunks
    return (row << 6) + ((chunk ^ (row & 7)) << 3);
}

__global__ __launch_bounds__(256) void attn_k(const short* __restrict__ qb,
                                              const short* __restrict__ kb,
                                              const short* __restrict__ vtb,
                                              short* __restrict__ yb) {
    __shared__ __align__(16) short Ks[64*128];   // [key][d] (chunk-swizzled)
    __shared__ __align__(16) short Vs[128*64];   // [d][key] (chunk-swizzled)
    __shared__ __align__(16) short Ps[4][16*72]; // per-wave P [16 q][64+8 pad]
    const int bid = blockIdx.x;
    const int qt = bid & 31;
    const int h  = (bid >> 5) & 31;
    const int b  = bid >> 10;
    const int kv = h >> 2;
    const int t = threadIdx.x, lane = t & 63, w = t >> 6;
    const int l16 = lane & 15, lhi = lane >> 4;
    const short* Qp = qb  + ((((size_t)b*NHEAD + h)*SEQ + qt*64 + w*16) << 7);
    const short* Kp = kb  + (((size_t)b*NKV + kv)*SEQ << 7);
    const short* Vp = vtb + (((size_t)b*NKV + kv)*SEQ << 7);   // HD*SEQ elems
    short8 qf[4];
#pragma unroll
    for (int kk = 0; kk < 4; ++kk)
        qf[kk] = *(const short8*)&Qp[l16*HD + kk*32 + lhi*8];
    f32x4 oacc[8] = {};
    float mrow[4] = {-1e30f, -1e30f, -1e30f, -1e30f};
    float lsum[4] = {};
    const float sc = 0.08838834764831845f;   // 1/sqrt(128)
    for (int kt = 0; kt <= qt; ++kt) {
        // stage K tile [64][128]: LDS linear, global chunk pre-swizzled
#pragma unroll
        for (int i = 0; i < 4; ++i) {
            int C = i*256 + t;                 // 16B chunk index
            int r = C >> 4, s = C & 15;
            gload_lds16(Kp + (size_t)kt*64*HD + r*128 + ((s ^ (r & 7)) << 3), &Ks[C*8]);
        }
        // stage Vt tile [128][64]
#pragma unroll
        for (int i = 0; i < 4; ++i) {
            int C = i*256 + t;
            int r = C >> 3, s = C & 7;
            gload_lds16(Vp + (size_t)r*SEQ + kt*64 + ((s ^ (r & 7)) << 3), &Vs[C*8]);
        }
        __syncthreads();
        // S = Q K^T  (rows q=lhi*4+r, cols key=n*16+l16 in C layout)
        f32x4 sfr[4] = {};
#pragma unroll
        for (int kk = 0; kk < 4; ++kk) {
#pragma unroll
            for (int n = 0; n < 4; ++n) {
                short8 kf = *(const short8*)&Ks[swzK(n*16 + l16, kk*4 + lhi)];
                sfr[n] = __builtin_amdgcn_mfma_f32_16x16x32_bf16(qf[kk], kf, sfr[n], 0, 0, 0);
            }
        }
        // scale + causal mask + tile row-max
        float tmax[4] = {-1e30f, -1e30f, -1e30f, -1e30f};
#pragma unroll
        for (int n = 0; n < 4; ++n)
#pragma unroll
            for (int r = 0; r < 4; ++r) {
                float sv = sfr[n][r] * sc;
                if (kt == qt && (n*16 + l16) > (w*16 + lhi*4 + r)) sv = -1e30f;
                sfr[n][r] = sv;
                tmax[r] = fmaxf(tmax[r], sv);
            }
#pragma unroll
        for (int off = 1; off < 16; off <<= 1)
#pragma unroll
            for (int r = 0; r < 4; ++r)
                tmax[r] = fmaxf(tmax[r], __shfl_xor(tmax[r], off, 64));
        float alpha[4], rsum[4];
#pragma unroll
        for (int r = 0; r < 4; ++r) {
            float mn = fmaxf(mrow[r], tmax[r]);
            alpha[r] = __expf(mrow[r] - mn);
            mrow[r] = mn;
            rsum[r] = 0.f;
        }
#pragma unroll
        for (int n = 0; n < 4; ++n)
#pragma unroll
            for (int r = 0; r < 4; ++r) {
                float p = __expf(sfr[n][r] - mrow[r]);
                sfr[n][r] = p;
                rsum[r] += p;
            }
#pragma unroll
        for (int off = 1; off < 16; off <<= 1)
#pragma unroll
            for (int r = 0; r < 4; ++r)
                rsum[r] += __shfl_xor(rsum[r], off, 64);
#pragma unroll
        for (int r = 0; r < 4; ++r)
            lsum[r] = lsum[r]*alpha[r] + rsum[r];
#pragma unroll
        for (int n = 0; n < 8; ++n)
#pragma unroll
            for (int r = 0; r < 4; ++r)
                oacc[n][r] *= alpha[r];
        // P -> LDS (per-wave private, padded rows: no barrier needed)
#pragma unroll
        for (int n = 0; n < 4; ++n)
#pragma unroll
            for (int r = 0; r < 4; ++r)
                Ps[w][(lhi*4 + r)*72 + n*16 + l16] = f2bf(sfr[n][r]);
        // O += P V
#pragma unroll
        for (int kk2 = 0; kk2 < 2; ++kk2) {
            short8 pf = *(const short8*)&Ps[w][l16*72 + kk2*32 + lhi*8];
#pragma unroll
            for (int n = 0; n < 8; ++n) {
                short8 vf = *(const short8*)&Vs[swzV(n*16 + l16, kk2*4 + lhi)];
                oacc[n] = __builtin_amdgcn_mfma_f32_16x16x32_bf16(pf, vf, oacc[n], 0, 0, 0);
            }
        }
        __syncthreads();   // protect Ks/Vs before next stage
    }
    float inv[4];
#pragma unroll
    for (int r = 0; r < 4; ++r) inv[r] = 1.f / lsum[r];
#pragma unroll
    for (int n = 0; n < 8; ++n)
#pragma unroll
        for (int r = 0; r < 4; ++r) {
            size_t row = (size_t)b*SEQ + qt*64 + w*16 + lhi*4 + r;
            yb[row*DIM + h*HD + n*16 + l16] = f2bf(oacc[n][r] * inv[r]);
        }
}

// ---------------- launch ----------------
extern "C" void kernel_launch(void* const* d_in, const int* in_sizes, int n_in,
                              void* d_out, int out_size, void* d_ws, size_t ws_size,
                              hipStream_t stream) {
    const float* x     = (const float*)d_in[0];
    const float* freqs = (const float*)d_in[1];
    // d_in[2] mask_cache (causal tril — hard-coded), d_in[3] input_pos (arange — unused)
    const float* wqkv  = (const float*)d_in[4];
    const float* wo    = (const float*)d_in[5];
    float* out = (float*)d_out;
    char* ws = (char*)d_ws;
    const size_t MB = 1024*1024;
    short* xb    = (short*)ws;              // 32MB  (later reused as yb)
    short* yb    = (short*)ws;
    short* wqkvb = (short*)(ws + 32*MB);    // 48MB  (later reused as wob)
    short* wob   = (short*)(ws + 32*MB);
    short* qkvb  = (short*)(ws + 80*MB);    // 48MB
    short* qb    = (short*)(ws + 128*MB);   // 32MB
    short* kb    = (short*)(ws + 160*MB);   // 8MB
    short* vtb   = (short*)(ws + 168*MB);   // 8MB  (total 176MB)

    f2bf_k<<<(DIM*DIM/4 + 255)/256, 256, 0, stream>>>(x, xb, DIM*DIM/4);
    f2bf_k<<<(NF*DIM/4 + 255)/256, 256, 0, stream>>>(wqkv, wqkvb, NF*DIM/4);
    gemm_bt<1><<<(M1/128)*(NF/128), 256, 0, stream>>>(xb, wqkvb, qkvb, M1, NF, DIM);
    rope_split_k<<<(M1*(NF/8) + 255)/256, 256, 0, stream>>>(qkvb, freqs, qb, kb, vtb);
    attn_k<<<BATCH*NHEAD*(SEQ/64), 256, 0, stream>>>(qb, kb, vtb, yb);      // yb over xb: safe
    f2bf_k<<<(DIM*DIM/4 + 255)/256, 256, 0, stream>>>(wo, wob, DIM*DIM/4);  // wob over wqkvb: safe
    gemm_bt<0><<<(M1/128)*(DIM/128), 256, 0, stream>>>(yb, wob, out, M1, DIM, DIM);
}

// Round 2
// 683.587 us; speedup vs baseline: 1.2638x; 1.2638x over previous
//
#include <hip/hip_runtime.h>
#include <hip/hip_bf16.h>

#define DIM   4096
#define NHEAD 32
#define NKV   8
#define HD    128
#define BATCH 2
#define SEQ   2048
#define M1    (BATCH*SEQ)           // 4096 rows of x
#define NF    ((NHEAD+2*NKV)*HD)    // 6144 qkv features

typedef __attribute__((ext_vector_type(8))) short short8;
typedef __attribute__((ext_vector_type(4))) short short4v;
typedef __attribute__((ext_vector_type(4))) float f32x4;

__device__ __forceinline__ float bf2f(short s) {
    unsigned u = ((unsigned)(unsigned short)s) << 16;
    return __builtin_bit_cast(float, u);
}
__device__ __forceinline__ short f2bf(float f) {
    unsigned u = __builtin_bit_cast(unsigned, f);
    u = u + 0x7fffu + ((u >> 16) & 1u);   // RNE
    return (short)(u >> 16);
}

__device__ __forceinline__ void gload_lds16(const void* g, void* l) {
    __builtin_amdgcn_global_load_lds(
        (const __attribute__((address_space(1))) void*)g,
        (__attribute__((address_space(3))) void*)l, 16, 0, 0);
}

// ---------------- fp32 -> bf16 convert ----------------
__global__ void f2bf_k(const float* __restrict__ src, short* __restrict__ dst, int n4) {
    int i = blockIdx.x * blockDim.x + threadIdx.x;
    if (i >= n4) return;
    float4 v = ((const float4*)src)[i];
    short4v o;
    o[0] = f2bf(v.x); o[1] = f2bf(v.y); o[2] = f2bf(v.z); o[3] = f2bf(v.w);
    ((short4v*)dst)[i] = o;
}

// ---------------- GEMM  C[M][N] = A[M][K] * Bm[N][K]^T  (m97 structure) ----------------
template<int OUT_BF16>
__global__ __launch_bounds__(256) void gemm_bt(const short* __restrict__ A,
                                               const short* __restrict__ Bm,
                                               void* __restrict__ Cout,
                                               int M, int N, int K) {
    __shared__ __align__(16) short As[128*64];
    __shared__ __align__(16) short Bs[128*64];
    const int nb   = N >> 7;
    const int brow = blockIdx.x / nb, bcol = blockIdx.x % nb;
    const int t    = threadIdx.x;
    const int lane = t & 63, w = t >> 6;
    const int wr = (w >> 1) * 64, wc = (w & 1) * 64;
    const int l16 = lane & 15, lhi = lane >> 4;
    f32x4 acc[4][4] = {};
    const size_t abase = (size_t)(brow * 128) * K;
    const size_t bbase = (size_t)(bcol * 128) * K;
    for (int k0 = 0; k0 < K; k0 += 64) {
#pragma unroll
        for (int i = 0; i < 4; ++i) {
            int e = (i * 256 + t) * 8;
            int r = e >> 6, c = e & 63;
            gload_lds16(A + abase + (size_t)r * K + k0 + c, &As[e]);
        }
#pragma unroll
        for (int i = 0; i < 4; ++i) {
            int e = (i * 256 + t) * 8;
            int r = e >> 6, c = e & 63;
            gload_lds16(Bm + bbase + (size_t)r * K + k0 + c, &Bs[e]);
        }
        __syncthreads();
#pragma unroll
        for (int kk = 0; kk < 2; ++kk) {
            short8 a[4], b[4];
#pragma unroll
            for (int m = 0; m < 4; ++m)
                a[m] = *(const short8*)&As[(wr + m*16 + l16)*64 + kk*32 + lhi*8];
#pragma unroll
            for (int n = 0; n < 4; ++n)
                b[n] = *(const short8*)&Bs[(wc + n*16 + l16)*64 + kk*32 + lhi*8];
#pragma unroll
            for (int m = 0; m < 4; ++m)
#pragma unroll
                for (int n = 0; n < 4; ++n)
                    acc[m][n] = __builtin_amdgcn_mfma_f32_16x16x32_bf16(a[m], b[n], acc[m][n], 0, 0, 0);
        }
        __syncthreads();
    }
#pragma unroll
    for (int m = 0; m < 4; ++m)
#pragma unroll
        for (int n = 0; n < 4; ++n)
#pragma unroll
            for (int r = 0; r < 4; ++r) {
                size_t row = brow*128 + wr + m*16 + lhi*4 + r;
                size_t col = bcol*128 + wc + n*16 + l16;
                if (OUT_BF16)
                    ((short*)Cout)[row * N + col] = f2bf(acc[m][n][r]);
                else
                    ((float*)Cout)[row * N + col] = acc[m][n][r];
            }
}

// ---------------- RoPE + split + V repack ----------------
// qkv bf16 [M1][NF]; freqs fp32 [SEQ][64][2]
// qb [B][NHEAD][SEQ][HD], kb [B][NKV][SEQ][HD]
// vg [B][NKV][SEQ/32][HD][32]   (per-32-key tile, V^T within tile: [d][key])
__global__ void rope_split_k(const short* __restrict__ qkv,
                             const float* __restrict__ freqs,
                             short* __restrict__ qb, short* __restrict__ kb,
                             short* __restrict__ vg) {
    int tid  = blockIdx.x * blockDim.x + threadIdx.x;   // one per 8 elems
    int colg = tid % (NF / 8);
    int row  = tid / (NF / 8);
    if (row >= M1) return;
    int b = row >> 11, s = row & 2047;
    int f = colg << 3;
    int h = f >> 7, d = f & 127;
    short8 v = *(const short8*)&qkv[(size_t)row * NF + f];
    if (h < NHEAD + NKV) {
        const float4 fa = *(const float4*)&freqs[(size_t)(s*64 + (d>>1)) * 2];
        const float4 fb = *(const float4*)&freqs[(size_t)(s*64 + (d>>1)) * 2 + 4];
        float fr[8] = {fa.x, fa.y, fa.z, fa.w, fb.x, fb.y, fb.z, fb.w};
        short8 o;
#pragma unroll
        for (int p = 0; p < 4; ++p) {
            float x0 = bf2f(v[2*p]), x1 = bf2f(v[2*p+1]);
            float c = fr[2*p], sn = fr[2*p+1];
            o[2*p]   = f2bf(x0 * c  - x1 * sn);
            o[2*p+1] = f2bf(x0 * sn + x1 * c);
        }
        if (h < NHEAD)
            *(short8*)&qb[((((size_t)b*NHEAD + h)*SEQ + s) << 7) + d] = o;
        else
            *(short8*)&kb[((((size_t)b*NKV + (h - NHEAD))*SEQ + s) << 7) + d] = o;
    } else {
        int kvh = h - NHEAD - NKV;
        size_t base = (((size_t)b*NKV + kvh) << 18) + (size_t)(s >> 5)*4096 + (s & 31);
#pragma unroll
        for (int j = 0; j < 8; ++j)
            vg[base + (size_t)(d + j) * 32] = v[j];
    }
}

// ---------------- flash attention (QBLK=128, KVB=32, dbuf, swapped QK) ----------------
__global__ __launch_bounds__(256, 3) void attn_k(const short* __restrict__ qb_,
                                                 const short* __restrict__ kb_,
                                                 const short* __restrict__ vg_,
                                                 short* __restrict__ yb) {
    __shared__ __align__(16) short Ks[2][32*128];   // [key][d], chunk-swizzled
    __shared__ __align__(16) short Vs[2][128*32];   // [d][key] per-tile, chunk-swizzled
    __shared__ __align__(16) short Pw[4][32*40];    // per-wave P [32 q][32 key + 8 pad]
    const int bid = blockIdx.x;
    const int qt = 15 - (bid >> 6);                 // heavy blocks dispatched first
    const int bh = bid & 63;
    const int b = bh >> 5, h = bh & 31, kv = h >> 2;
    const int t = threadIdx.x, lane = t & 63, w = t >> 6;
    const int l16 = lane & 15, lhi = lane >> 4;
    const short* Qp = qb_ + (((size_t)(b*NHEAD + h)*SEQ + qt*128 + w*32) << 7);
    const short* Kp = kb_ + (((size_t)(b*NKV + kv)*SEQ) << 7);
    const short* Vp = vg_ + (((size_t)(b*NKV + kv)*SEQ) << 7);
    short8 qf[2][4];
#pragma unroll
    for (int qq = 0; qq < 2; ++qq)
#pragma unroll
        for (int kk = 0; kk < 4; ++kk)
            qf[qq][kk] = *(const short8*)&Qp[(qq*16 + l16)*HD + kk*32 + lhi*8];
    f32x4 oacc[2][8] = {};
    float mrow[2] = {-1e30f, -1e30f};
    float lsum[2] = {0.f, 0.f};
    const int NT = (qt + 1) * 4;
    const int qmaxw = qt*128 + w*32 + 31;
    const float sc = 0.08838834764831845f;   // 1/sqrt(128)

    auto stage = [&](int kt, int buf) {
#pragma unroll
        for (int i = 0; i < 2; ++i) {          // K tile: 32 rows x 16 chunks
            int L = i*256 + t;
            int r = L >> 4, s = L & 15;
            int gs = (s & 8) | ((s & 7) ^ (r & 7));
            gload_lds16(Kp + (size_t)kt*4096 + r*128 + gs*8, &Ks[buf][L*8]);
        }
#pragma unroll
        for (int i = 0; i < 2; ++i) {          // V tile: 512 chunks, 8-chunk stripes
            int L = i*256 + t;
            int r8 = L >> 3, s3 = L & 7;
            int gs = s3 ^ (r8 & 7);
            gload_lds16(Vp + (size_t)kt*4096 + (r8*8 + gs)*8, &Vs[buf][L*8]);
        }
    };

    stage(0, 0);
    __syncthreads();
    int cur = 0;
    for (int kt = 0; kt < NT; ++kt) {
        if (kt + 1 < NT) stage(kt + 1, cur ^ 1);
        if (kt*32 <= qmaxw) {
            // S^T = K Q^T : row=key (kb*16+lhi*4+r), col=q (qq*16+l16)
            f32x4 sT[2][2] = {};
#pragma unroll
            for (int kk = 0; kk < 4; ++kk) {
                short8 kf[2];
#pragma unroll
                for (int kb2 = 0; kb2 < 2; ++kb2) {
                    int row = kb2*16 + l16;
                    int ch  = kk*4 + lhi;
                    int chs = (ch & 8) | ((ch & 7) ^ (row & 7));
                    kf[kb2] = *(const short8*)&Ks[cur][row*128 + chs*8];
                }
#pragma unroll
                for (int kb2 = 0; kb2 < 2; ++kb2)
#pragma unroll
                    for (int qq = 0; qq < 2; ++qq)
                        sT[kb2][qq] = __builtin_amdgcn_mfma_f32_16x16x32_bf16(kf[kb2], qf[qq][kk], sT[kb2][qq], 0, 0, 0);
            }
            // online softmax, per lane state for q = qq*16 + l16
#pragma unroll
            for (int qq = 0; qq < 2; ++qq) {
                int qg = qt*128 + w*32 + qq*16 + l16;
                float tmax = -1e30f;
#pragma unroll
                for (int kb2 = 0; kb2 < 2; ++kb2)
#pragma unroll
                    for (int r = 0; r < 4; ++r) {
                        int kg = kt*32 + kb2*16 + lhi*4 + r;
                        float sv = sT[kb2][qq][r] * sc;
                        sv = (kg > qg) ? -1e30f : sv;
                        sT[kb2][qq][r] = sv;
                        tmax = fmaxf(tmax, sv);
                    }
                tmax = fmaxf(tmax, __shfl_xor(tmax, 16, 64));
                tmax = fmaxf(tmax, __shfl_xor(tmax, 32, 64));
                float mn = fmaxf(mrow[qq], tmax);
                float alpha = __expf(mrow[qq] - mn);
                mrow[qq] = mn;
                float rsum = 0.f;
#pragma unroll
                for (int kb2 = 0; kb2 < 2; ++kb2) {
                    short4v pk;
#pragma unroll
                    for (int r = 0; r < 4; ++r) {
                        float p = __expf(sT[kb2][qq][r] - mn);
                        rsum += p;
                        pk[r] = f2bf(p);
                    }
                    *(short4v*)&Pw[w][(qq*16 + l16)*40 + kb2*16 + lhi*4] = pk;
                }
                rsum += __shfl_xor(rsum, 16, 64);
                rsum += __shfl_xor(rsum, 32, 64);
                lsum[qq] = lsum[qq]*alpha + rsum;
                // broadcast alpha to the lanes holding rows lhi*4+r of this q-block
                float a4[4];
#pragma unroll
                for (int r = 0; r < 4; ++r)
                    a4[r] = __shfl(alpha, (lane & 48) | (lhi*4 + r), 64);
#pragma unroll
                for (int n = 0; n < 8; ++n)
#pragma unroll
                    for (int r = 0; r < 4; ++r)
                        oacc[qq][n][r] *= a4[r];
            }
            // O += P V  (single k=32 MFMA per (qq,n))
            short8 pf[2];
#pragma unroll
            for (int qq = 0; qq < 2; ++qq)
                pf[qq] = *(const short8*)&Pw[w][(qq*16 + l16)*40 + lhi*8];
#pragma unroll
            for (int n = 0; n < 8; ++n) {
                int d   = n*16 + l16;
                int lch = d*4 + lhi;
                int phys = (lch & ~7) | ((lch & 7) ^ ((lch >> 3) & 7));
                short8 vf = *(const short8*)&Vs[cur][phys*8];
#pragma unroll
                for (int qq = 0; qq < 2; ++qq)
                    oacc[qq][n] = __builtin_amdgcn_mfma_f32_16x16x32_bf16(pf[qq], vf, oacc[qq][n], 0, 0, 0);
            }
        }
        __syncthreads();   // drains vmcnt: next buffer ready; protects cur buffer reuse
        cur ^= 1;
    }
#pragma unroll
    for (int qq = 0; qq < 2; ++qq) {
        float inv = 1.f / lsum[qq];
        float i4[4];
#pragma unroll
        for (int r = 0; r < 4; ++r)
            i4[r] = __shfl(inv, (lane & 48) | (lhi*4 + r), 64);
#pragma unroll
        for (int n = 0; n < 8; ++n)
#pragma unroll
            for (int r = 0; r < 4; ++r) {
                size_t row = (size_t)b*SEQ + qt*128 + w*32 + qq*16 + lhi*4 + r;
                yb[row*DIM + h*HD + n*16 + l16] = f2bf(oacc[qq][n][r] * i4[r]);
            }
    }
}

// ---------------- launch ----------------
extern "C" void kernel_launch(void* const* d_in, const int* in_sizes, int n_in,
                              void* d_out, int out_size, void* d_ws, size_t ws_size,
                              hipStream_t stream) {
    const float* x     = (const float*)d_in[0];
    const float* freqs = (const float*)d_in[1];
    // d_in[2] mask_cache (causal tril — hard-coded), d_in[3] input_pos (arange — unused)
    const float* wqkv  = (const float*)d_in[4];
    const float* wo    = (const float*)d_in[5];
    float* out = (float*)d_out;
    char* ws = (char*)d_ws;
    const size_t MB = 1024*1024;
    short* xb    = (short*)ws;              // 32MB  (later reused as yb)
    short* yb    = (short*)ws;
    short* wqkvb = (short*)(ws + 32*MB);    // 48MB  (later reused as wob)
    short* wob   = (short*)(ws + 32*MB);
    short* qkvb  = (short*)(ws + 80*MB);    // 48MB
    short* qb    = (short*)(ws + 128*MB);   // 32MB
    short* kb    = (short*)(ws + 160*MB);   // 8MB
    short* vg    = (short*)(ws + 168*MB);   // 8MB  (total 176MB)

    f2bf_k<<<(DIM*DIM/4 + 255)/256, 256, 0, stream>>>(x, xb, DIM*DIM/4);
    f2bf_k<<<(NF*DIM/4 + 255)/256, 256, 0, stream>>>(wqkv, wqkvb, NF*DIM/4);
    gemm_bt<1><<<(M1/128)*(NF/128), 256, 0, stream>>>(xb, wqkvb, qkvb, M1, NF, DIM);
    rope_split_k<<<(M1*(NF/8) + 255)/256, 256, 0, stream>>>(qkvb, freqs, qb, kb, vg);
    attn_k<<<BATCH*NHEAD*(SEQ/128), 256, 0, stream>>>(qb, kb, vg, yb);      // yb over xb: safe
    f2bf_k<<<(DIM*DIM/4 + 255)/256, 256, 0, stream>>>(wo, wob, DIM*DIM/4);  // wob over wqkvb: safe
    gemm_bt<0><<<(M1/128)*(DIM/128), 256, 0, stream>>>(yb, wob, out, M1, DIM, DIM);
}

// Round 3
// 596.977 us; speedup vs baseline: 1.4472x; 1.1451x over previous
//
#include <hip/hip_runtime.h>
#include <hip/hip_bf16.h>

#define DIM   4096
#define NHEAD 32
#define NKV   8
#define HD    128
#define BATCH 2
#define SEQ   2048
#define M1    (BATCH*SEQ)           // 4096 rows of x
#define NF    ((NHEAD+2*NKV)*HD)    // 6144 qkv features

typedef __attribute__((ext_vector_type(8))) short short8;
typedef __attribute__((ext_vector_type(4))) short short4v;
typedef __attribute__((ext_vector_type(4))) float f32x4;

__device__ __forceinline__ float bf2f(short s) {
    unsigned u = ((unsigned)(unsigned short)s) << 16;
    return __builtin_bit_cast(float, u);
}
__device__ __forceinline__ short f2bf(float f) {
    unsigned u = __builtin_bit_cast(unsigned, f);
    u = u + 0x7fffu + ((u >> 16) & 1u);   // RNE
    return (short)(u >> 16);
}

__device__ __forceinline__ void gload_lds16(const void* g, void* l) {
    __builtin_amdgcn_global_load_lds(
        (const __attribute__((address_space(1))) void*)g,
        (__attribute__((address_space(3))) void*)l, 16, 0, 0);
}

// ---------------- fp32 -> bf16 convert ----------------
__global__ void f2bf_k(const float* __restrict__ src, short* __restrict__ dst, int n4) {
    int i = blockIdx.x * blockDim.x + threadIdx.x;
    if (i >= n4) return;
    float4 v = ((const float4*)src)[i];
    short4v o;
    o[0] = f2bf(v.x); o[1] = f2bf(v.y); o[2] = f2bf(v.z); o[3] = f2bf(v.w);
    ((short4v*)dst)[i] = o;
}

// ============ 256x256 8-phase GEMM  C[M][N] = A[M][K] * Bm[N][K]^T ============
// 512 thr = 8 waves (2m x 4n); per-wave C = 128x64 = acc[8][4] f32x4.
// LDS 128KB: As[d][qm][128][64], Bs[d][qn][128][64]; chunk^(row&7) swizzle,
// staged via global_load_lds (linear dest, inverse-swizzled global src).
// Per tile: 4 phases (C-quadrants). Stage slots: mod0->A-q1(cur+1),
// mod1->B-q1(cur+1), mod2->A-q0(cur+2), mod3->B-q0(cur+2). Counted waits:
// vmcnt(4)@mod0, vmcnt(6)@mod3, certified cross-wave by that phase's
// mid-barrier one phase before first consumption. vmcnt never drains to 0.
template<int OUT_BF16>
__global__ __launch_bounds__(512, 2) void gemm256(const short* __restrict__ A,
                                                  const short* __restrict__ Bm,
                                                  void* __restrict__ Cout,
                                                  int M, int N, int K) {
    __shared__ __align__(16) short As[2][2][128*64];   // 64KB
    __shared__ __align__(16) short Bs[2][2][128*64];   // 64KB
    const int nbn = N >> 8;
    const int nwg = gridDim.x;
    const int cpx = nwg >> 3;
    const int swz = (blockIdx.x & 7) * cpx + (blockIdx.x >> 3);  // grids are %8==0
    const int brow = swz / nbn, bcol = swz % nbn;
    const int t = threadIdx.x, lane = t & 63, w = t >> 6;
    const int wm = w >> 2, wn = w & 3;
    const int l16 = lane & 15, lhi = lane >> 4, l7 = l16 & 7;
    const size_t abase = (size_t)brow * 256 * K;
    const size_t bbase = (size_t)bcol * 256 * K;
    const int sr = t >> 3;              // staging row-within-unit 0..63
    const int sc = t & 7;               // phys chunk
    const int scl = sc ^ (sr & 7);      // logical chunk this thread fetches
    f32x4 acc[8][4] = {};

    auto stageA = [&](int kt, int qm) {
#pragma unroll
        for (int i = 0; i < 2; ++i)
            gload_lds16(A + abase + (size_t)(i*128 + qm*64 + sr) * K + kt*64 + scl*8,
                        &As[kt & 1][qm][(i*64 + sr)*64 + sc*8]);
    };
    auto stageB = [&](int kt, int qn) {
#pragma unroll
        for (int i = 0; i < 2; ++i)
            gload_lds16(Bm + bbase + (size_t)((i*2 + (sr>>5))*64 + qn*32 + (sr & 31)) * K + kt*64 + scl*8,
                        &Bs[kt & 1][qn][(i*64 + sr)*64 + sc*8]);
    };

    const int NT = K >> 6;
    // prologue: units in issue order A-q0(0) B-q0(0) A-q1(0) B-q1(0) A-q0(1) B-q0(1)
    stageA(0, 0); stageB(0, 0); stageA(0, 1); stageB(0, 1);
    stageA(1, 0); stageB(1, 0);
    asm volatile("s_waitcnt vmcnt(4)" ::: "memory");   // tile0 fully landed (own)
    __builtin_amdgcn_s_barrier();                      // ...and cross-wave

#define PHASE(QM, QN, VMW, STAGE_STMT)                                          \
    {                                                                           \
        VMW;                                                                    \
        short8 afr[4][2], bfr[2][2];                                            \
        _Pragma("unroll") for (int mi = 0; mi < 4; ++mi)                        \
        _Pragma("unroll") for (int kk = 0; kk < 2; ++kk)                        \
            afr[mi][kk] = *(const short8*)&As[d][QM][(wm*64 + mi*16 + l16)*64 + (((kk*4 + lhi) ^ l7) * 8)]; \
        _Pragma("unroll") for (int ni = 0; ni < 2; ++ni)                        \
        _Pragma("unroll") for (int kk = 0; kk < 2; ++kk)                        \
            bfr[ni][kk] = *(const short8*)&Bs[d][QN][(wn*32 + ni*16 + l16)*64 + (((kk*4 + lhi) ^ l7) * 8)]; \
        STAGE_STMT;                                                             \
        __builtin_amdgcn_s_barrier();                                           \
        __builtin_amdgcn_s_setprio(1);                                          \
        _Pragma("unroll") for (int kk = 0; kk < 2; ++kk)                        \
        _Pragma("unroll") for (int mi = 0; mi < 4; ++mi)                        \
        _Pragma("unroll") for (int ni = 0; ni < 2; ++ni)                        \
            acc[QM*4 + mi][QN*2 + ni] = __builtin_amdgcn_mfma_f32_16x16x32_bf16( \
                afr[mi][kk], bfr[ni][kk], acc[QM*4 + mi][QN*2 + ni], 0, 0, 0);  \
        __builtin_amdgcn_s_setprio(0);                                          \
        __builtin_amdgcn_s_barrier();                                           \
    }

    for (int cur = 0; cur < NT; ++cur) {
        const int d = cur & 1;
        PHASE(0, 0, asm volatile("s_waitcnt vmcnt(4)" ::: "memory"),
              { if (cur + 1 < NT) stageA(cur + 1, 1); })
        PHASE(0, 1, ,
              { if (cur + 1 < NT) stageB(cur + 1, 1); })
        PHASE(1, 0, ,
              { if (cur + 2 < NT) stageA(cur + 2, 0); })
        PHASE(1, 1, asm volatile("s_waitcnt vmcnt(6)" ::: "memory"),
              { if (cur + 2 < NT) stageB(cur + 2, 0); })
    }
#undef PHASE

#pragma unroll
    for (int fm = 0; fm < 8; ++fm)
#pragma unroll
        for (int fn = 0; fn < 4; ++fn)
#pragma unroll
            for (int r = 0; r < 4; ++r) {
                size_t row = (size_t)brow*256 + wm*128 + fm*16 + lhi*4 + r;
                size_t col = (size_t)bcol*256 + wn*64 + fn*16 + l16;
                if (OUT_BF16)
                    ((short*)Cout)[row * N + col] = f2bf(acc[fm][fn][r]);
                else
                    ((float*)Cout)[row * N + col] = acc[fm][fn][r];
            }
}

// ---------------- RoPE + split + V repack ----------------
// qkv bf16 [M1][NF]; freqs fp32 [SEQ][64][2]
// qb [B][NHEAD][SEQ][HD], kb [B][NKV][SEQ][HD]
// vg [B][NKV][SEQ/32][HD][32]   (per-32-key tile, V^T within tile: [d][key])
__global__ void rope_split_k(const short* __restrict__ qkv,
                             const float* __restrict__ freqs,
                             short* __restrict__ qb, short* __restrict__ kb,
                             short* __restrict__ vg) {
    int tid  = blockIdx.x * blockDim.x + threadIdx.x;   // one per 8 elems
    int colg = tid % (NF / 8);
    int row  = tid / (NF / 8);
    if (row >= M1) return;
    int b = row >> 11, s = row & 2047;
    int f = colg << 3;
    int h = f >> 7, d = f & 127;
    short8 v = *(const short8*)&qkv[(size_t)row * NF + f];
    if (h < NHEAD + NKV) {
        const float4 fa = *(const float4*)&freqs[(size_t)(s*64 + (d>>1)) * 2];
        const float4 fb = *(const float4*)&freqs[(size_t)(s*64 + (d>>1)) * 2 + 4];
        float fr[8] = {fa.x, fa.y, fa.z, fa.w, fb.x, fb.y, fb.z, fb.w};
        short8 o;
#pragma unroll
        for (int p = 0; p < 4; ++p) {
            float x0 = bf2f(v[2*p]), x1 = bf2f(v[2*p+1]);
            float c = fr[2*p], sn = fr[2*p+1];
            o[2*p]   = f2bf(x0 * c  - x1 * sn);
            o[2*p+1] = f2bf(x0 * sn + x1 * c);
        }
        if (h < NHEAD)
            *(short8*)&qb[((((size_t)b*NHEAD + h)*SEQ + s) << 7) + d] = o;
        else
            *(short8*)&kb[((((size_t)b*NKV + (h - NHEAD))*SEQ + s) << 7) + d] = o;
    } else {
        int kvh = h - NHEAD - NKV;
        size_t base = (((size_t)b*NKV + kvh) << 18) + (size_t)(s >> 5)*4096 + (s & 31);
#pragma unroll
        for (int j = 0; j < 8; ++j)
            vg[base + (size_t)(d + j) * 32] = v[j];
    }
}

// ---------------- flash attention (QBLK=128, KVB=32, dbuf, swapped QK) ----------------
__global__ __launch_bounds__(256, 3) void attn_k(const short* __restrict__ qb_,
                                                 const short* __restrict__ kb_,
                                                 const short* __restrict__ vg_,
                                                 short* __restrict__ yb) {
    __shared__ __align__(16) short Ks[2][32*128];   // [key][d], chunk-swizzled
    __shared__ __align__(16) short Vs[2][128*32];   // [d][key] per-tile, chunk-swizzled
    __shared__ __align__(16) short Pw[4][32*40];    // per-wave P [32 q][32 key + 8 pad]
    const int bid = blockIdx.x;
    const int qt = 15 - (bid >> 6);                 // heavy blocks dispatched first
    const int bh = bid & 63;
    const int b = bh >> 5, h = bh & 31, kv = h >> 2;
    const int t = threadIdx.x, lane = t & 63, w = t >> 6;
    const int l16 = lane & 15, lhi = lane >> 4;
    const short* Qp = qb_ + (((size_t)(b*NHEAD + h)*SEQ + qt*128 + w*32) << 7);
    const short* Kp = kb_ + (((size_t)(b*NKV + kv)*SEQ) << 7);
    const short* Vp = vg_ + (((size_t)(b*NKV + kv)*SEQ) << 7);
    short8 qf[2][4];
#pragma unroll
    for (int qq = 0; qq < 2; ++qq)
#pragma unroll
        for (int kk = 0; kk < 4; ++kk)
            qf[qq][kk] = *(const short8*)&Qp[(qq*16 + l16)*HD + kk*32 + lhi*8];
    f32x4 oacc[2][8] = {};
    float mrow[2] = {-1e30f, -1e30f};
    float lsum[2] = {0.f, 0.f};
    const int NT = (qt + 1) * 4;
    const int qmaxw = qt*128 + w*32 + 31;
    const float sc = 0.08838834764831845f;   // 1/sqrt(128)

    auto stage = [&](int kt, int buf) {
#pragma unroll
        for (int i = 0; i < 2; ++i) {          // K tile: 32 rows x 16 chunks
            int L = i*256 + t;
            int r = L >> 4, s = L & 15;
            int gs = (s & 8) | ((s & 7) ^ (r & 7));
            gload_lds16(Kp + (size_t)kt*4096 + r*128 + gs*8, &Ks[buf][L*8]);
        }
#pragma unroll
        for (int i = 0; i < 2; ++i) {          // V tile: 512 chunks, 8-chunk stripes
            int L = i*256 + t;
            int r8 = L >> 3, s3 = L & 7;
            int gs = s3 ^ (r8 & 7);
            gload_lds16(Vp + (size_t)kt*4096 + (r8*8 + gs)*8, &Vs[buf][L*8]);
        }
    };

    stage(0, 0);
    __syncthreads();
    int cur = 0;
    for (int kt = 0; kt < NT; ++kt) {
        if (kt + 1 < NT) stage(kt + 1, cur ^ 1);
        if (kt*32 <= qmaxw) {
            // S^T = K Q^T : row=key (kb*16+lhi*4+r), col=q (qq*16+l16)
            f32x4 sT[2][2] = {};
#pragma unroll
            for (int kk = 0; kk < 4; ++kk) {
                short8 kf[2];
#pragma unroll
                for (int kb2 = 0; kb2 < 2; ++kb2) {
                    int row = kb2*16 + l16;
                    int ch  = kk*4 + lhi;
                    int chs = (ch & 8) | ((ch & 7) ^ (row & 7));
                    kf[kb2] = *(const short8*)&Ks[cur][row*128 + chs*8];
                }
#pragma unroll
                for (int kb2 = 0; kb2 < 2; ++kb2)
#pragma unroll
                    for (int qq = 0; qq < 2; ++qq)
                        sT[kb2][qq] = __builtin_amdgcn_mfma_f32_16x16x32_bf16(kf[kb2], qf[qq][kk], sT[kb2][qq], 0, 0, 0);
            }
            // online softmax, per lane state for q = qq*16 + l16
#pragma unroll
            for (int qq = 0; qq < 2; ++qq) {
                int qg = qt*128 + w*32 + qq*16 + l16;
                float tmax = -1e30f;
#pragma unroll
                for (int kb2 = 0; kb2 < 2; ++kb2)
#pragma unroll
                    for (int r = 0; r < 4; ++r) {
                        int kg = kt*32 + kb2*16 + lhi*4 + r;
                        float sv = sT[kb2][qq][r] * sc;
                        sv = (kg > qg) ? -1e30f : sv;
                        sT[kb2][qq][r] = sv;
                        tmax = fmaxf(tmax, sv);
                    }
                tmax = fmaxf(tmax, __shfl_xor(tmax, 16, 64));
                tmax = fmaxf(tmax, __shfl_xor(tmax, 32, 64));
                float mn = fmaxf(mrow[qq], tmax);
                float alpha = __expf(mrow[qq] - mn);
                mrow[qq] = mn;
                float rsum = 0.f;
#pragma unroll
                for (int kb2 = 0; kb2 < 2; ++kb2) {
                    short4v pk;
#pragma unroll
                    for (int r = 0; r < 4; ++r) {
                        float p = __expf(sT[kb2][qq][r] - mn);
                        rsum += p;
                        pk[r] = f2bf(p);
                    }
                    *(short4v*)&Pw[w][(qq*16 + l16)*40 + kb2*16 + lhi*4] = pk;
                }
                rsum += __shfl_xor(rsum, 16, 64);
                rsum += __shfl_xor(rsum, 32, 64);
                lsum[qq] = lsum[qq]*alpha + rsum;
                // broadcast alpha to the lanes holding rows lhi*4+r of this q-block
                float a4[4];
#pragma unroll
                for (int r = 0; r < 4; ++r)
                    a4[r] = __shfl(alpha, (lane & 48) | (lhi*4 + r), 64);
#pragma unroll
                for (int n = 0; n < 8; ++n)
#pragma unroll
                    for (int r = 0; r < 4; ++r)
                        oacc[qq][n][r] *= a4[r];
            }
            // O += P V  (single k=32 MFMA per (qq,n))
            short8 pf[2];
#pragma unroll
            for (int qq = 0; qq < 2; ++qq)
                pf[qq] = *(const short8*)&Pw[w][(qq*16 + l16)*40 + lhi*8];
#pragma unroll
            for (int n = 0; n < 8; ++n) {
                int d   = n*16 + l16;
                int lch = d*4 + lhi;
                int phys = (lch & ~7) | ((lch & 7) ^ ((lch >> 3) & 7));
                short8 vf = *(const short8*)&Vs[cur][phys*8];
#pragma unroll
                for (int qq = 0; qq < 2; ++qq)
                    oacc[qq][n] = __builtin_amdgcn_mfma_f32_16x16x32_bf16(pf[qq], vf, oacc[qq][n], 0, 0, 0);
            }
        }
        __syncthreads();   // drains vmcnt: next buffer ready; protects cur buffer reuse
        cur ^= 1;
    }
#pragma unroll
    for (int qq = 0; qq < 2; ++qq) {
        float inv = 1.f / lsum[qq];
        float i4[4];
#pragma unroll
        for (int r = 0; r < 4; ++r)
            i4[r] = __shfl(inv, (lane & 48) | (lhi*4 + r), 64);
#pragma unroll
        for (int n = 0; n < 8; ++n)
#pragma unroll
            for (int r = 0; r < 4; ++r) {
                size_t row = (size_t)b*SEQ + qt*128 + w*32 + qq*16 + lhi*4 + r;
                yb[row*DIM + h*HD + n*16 + l16] = f2bf(oacc[qq][n][r] * i4[r]);
            }
    }
}

// ---------------- launch ----------------
extern "C" void kernel_launch(void* const* d_in, const int* in_sizes, int n_in,
                              void* d_out, int out_size, void* d_ws, size_t ws_size,
                              hipStream_t stream) {
    const float* x     = (const float*)d_in[0];
    const float* freqs = (const float*)d_in[1];
    // d_in[2] mask_cache (causal tril — hard-coded), d_in[3] input_pos (arange — unused)
    const float* wqkv  = (const float*)d_in[4];
    const float* wo    = (const float*)d_in[5];
    float* out = (float*)d_out;
    char* ws = (char*)d_ws;
    const size_t MB = 1024*1024;
    short* xb    = (short*)ws;              // 32MB  (later reused as yb)
    short* yb    = (short*)ws;
    short* wqkvb = (short*)(ws + 32*MB);    // 48MB  (later reused as wob)
    short* wob   = (short*)(ws + 32*MB);
    short* qkvb  = (short*)(ws + 80*MB);    // 48MB
    short* qb    = (short*)(ws + 128*MB);   // 32MB
    short* kb    = (short*)(ws + 160*MB);   // 8MB
    short* vg    = (short*)(ws + 168*MB);   // 8MB  (total 176MB)

    f2bf_k<<<(DIM*DIM/4 + 255)/256, 256, 0, stream>>>(x, xb, DIM*DIM/4);
    f2bf_k<<<(NF*DIM/4 + 255)/256, 256, 0, stream>>>(wqkv, wqkvb, NF*DIM/4);
    gemm256<1><<<(M1/256)*(NF/256), 512, 0, stream>>>(xb, wqkvb, qkvb, M1, NF, DIM);
    rope_split_k<<<(M1*(NF/8) + 255)/256, 256, 0, stream>>>(qkvb, freqs, qb, kb, vg);
    attn_k<<<BATCH*NHEAD*(SEQ/128), 256, 0, stream>>>(qb, kb, vg, yb);      // yb over xb: safe
    f2bf_k<<<(DIM*DIM/4 + 255)/256, 256, 0, stream>>>(wo, wob, DIM*DIM/4);  // wob over wqkvb: safe
    gemm256<0><<<(M1/256)*(DIM/256), 512, 0, stream>>>(yb, wob, out, M1, DIM, DIM);
}

// Round 4
// 556.642 us; speedup vs baseline: 1.5520x; 1.0725x over previous
//
#include <hip/hip_runtime.h>
#include <hip/hip_bf16.h>

#define DIM   4096
#define NHEAD 32
#define NKV   8
#define HD    128
#define BATCH 2
#define SEQ   2048
#define M1    (BATCH*SEQ)           // 4096 rows of x
#define NF    ((NHEAD+2*NKV)*HD)    // 6144 qkv features

typedef __attribute__((ext_vector_type(8))) short short8;
typedef __attribute__((ext_vector_type(4))) short short4v;
typedef __attribute__((ext_vector_type(4))) float f32x4;

__device__ __forceinline__ float bf2f(short s) {
    unsigned u = ((unsigned)(unsigned short)s) << 16;
    return __builtin_bit_cast(float, u);
}
__device__ __forceinline__ short f2bf(float f) {
    unsigned u = __builtin_bit_cast(unsigned, f);
    u = u + 0x7fffu + ((u >> 16) & 1u);   // RNE
    return (short)(u >> 16);
}

__device__ __forceinline__ void gload_lds16(const void* g, void* l) {
    __builtin_amdgcn_global_load_lds(
        (const __attribute__((address_space(1))) void*)g,
        (__attribute__((address_space(3))) void*)l, 16, 0, 0);
}

// ---------------- fp32 -> bf16 convert ----------------
__global__ void f2bf_k(const float* __restrict__ src, short* __restrict__ dst, int n4) {
    int i = blockIdx.x * blockDim.x + threadIdx.x;
    if (i >= n4) return;
    float4 v = ((const float4*)src)[i];
    short4v o;
    o[0] = f2bf(v.x); o[1] = f2bf(v.y); o[2] = f2bf(v.z); o[3] = f2bf(v.w);
    ((short4v*)dst)[i] = o;
}

// ============ 256x256 8-phase GEMM  C[M][N] = A[M][K] * Bm[N][K]^T ============
// 512 thr = 8 waves (2m x 4n); per-wave C = 128x64 = acc[8][4] f32x4.
// Register-held fragments across phases: a0 loaded P0 (used P0,P1), b0 P0
// (P0,P2), b1 P1 (P1,P3), a1 P2 (P2,P3) -> 24 ds_read_b128 / wave / K-tile.
// Stage slots: P0->A-q1(cur+1), P1->B-q1(cur+1), P2->A-q0(cur+2),
// P3->B-q0(cur+2). Counted waits: vmcnt(4)@P0 (A1/B1 of cur landed),
// vmcnt(6)@P3 (A0/B0 of cur+2 landed), each certified cross-wave by that
// phase's barriers one phase before first consumption. Never drains to 0.
template<int OUT_BF16>
__global__ __launch_bounds__(512, 2) void gemm256(const short* __restrict__ A,
                                                  const short* __restrict__ Bm,
                                                  void* __restrict__ Cout,
                                                  int M, int N, int K) {
    __shared__ __align__(16) short As[2][2][128*64];   // 64KB
    __shared__ __align__(16) short Bs[2][2][128*64];   // 64KB
    const int nbn = N >> 8;
    const int nwg = gridDim.x;
    const int cpx = nwg >> 3;
    const int swz = (blockIdx.x & 7) * cpx + (blockIdx.x >> 3);  // grids are %8==0
    const int brow = swz / nbn, bcol = swz % nbn;
    const int t = threadIdx.x, lane = t & 63, w = t >> 6;
    const int wm = w >> 2, wn = w & 3;
    const int l16 = lane & 15, lhi = lane >> 4, l7 = l16 & 7;
    const size_t abase = (size_t)brow * 256 * K;
    const size_t bbase = (size_t)bcol * 256 * K;
    const int sr = t >> 3;              // staging row-within-unit 0..63
    const int sc = t & 7;               // phys chunk
    const int scl = sc ^ (sr & 7);      // logical chunk this thread fetches
    f32x4 acc[8][4] = {};

    auto stageA = [&](int kt, int qm) {
#pragma unroll
        for (int i = 0; i < 2; ++i)
            gload_lds16(A + abase + (size_t)(i*128 + qm*64 + sr) * K + kt*64 + scl*8,
                        &As[kt & 1][qm][(i*64 + sr)*64 + sc*8]);
    };
    auto stageB = [&](int kt, int qn) {
#pragma unroll
        for (int i = 0; i < 2; ++i)
            gload_lds16(Bm + bbase + (size_t)((i*2 + (sr>>5))*64 + qn*32 + (sr & 31)) * K + kt*64 + scl*8,
                        &Bs[kt & 1][qn][(i*64 + sr)*64 + sc*8]);
    };

    const int NT = K >> 6;
    // prologue: units in issue order A-q0(0) B-q0(0) A-q1(0) B-q1(0) A-q0(1) B-q0(1)
    stageA(0, 0); stageB(0, 0); stageA(0, 1); stageB(0, 1);
    stageA(1, 0); stageB(1, 0);
    asm volatile("s_waitcnt vmcnt(4)" ::: "memory");   // tile0 fully landed (own)
    __builtin_amdgcn_s_barrier();                      // ...and cross-wave

    short8 a0[4][2], a1[4][2], b0[2][2], b1[2][2];

#define LD_A(dst, QM)                                                           \
    _Pragma("unroll") for (int mi = 0; mi < 4; ++mi)                            \
    _Pragma("unroll") for (int kk = 0; kk < 2; ++kk)                            \
        dst[mi][kk] = *(const short8*)&As[d][QM][(wm*64 + mi*16 + l16)*64 + (((kk*4 + lhi) ^ l7) * 8)];
#define LD_B(dst, QN)                                                           \
    _Pragma("unroll") for (int ni = 0; ni < 2; ++ni)                            \
    _Pragma("unroll") for (int kk = 0; kk < 2; ++kk)                            \
        dst[ni][kk] = *(const short8*)&Bs[d][QN][(wn*32 + ni*16 + l16)*64 + (((kk*4 + lhi) ^ l7) * 8)];
#define MMA(QM, QN, af, bf)                                                     \
    __builtin_amdgcn_s_barrier();                                               \
    __builtin_amdgcn_s_setprio(1);                                              \
    _Pragma("unroll") for (int kk = 0; kk < 2; ++kk)                            \
    _Pragma("unroll") for (int mi = 0; mi < 4; ++mi)                            \
    _Pragma("unroll") for (int ni = 0; ni < 2; ++ni)                            \
        acc[QM*4 + mi][QN*2 + ni] = __builtin_amdgcn_mfma_f32_16x16x32_bf16(    \
            af[mi][kk], bf[ni][kk], acc[QM*4 + mi][QN*2 + ni], 0, 0, 0);        \
    __builtin_amdgcn_s_setprio(0);                                              \
    __builtin_amdgcn_s_barrier();

    for (int cur = 0; cur < NT; ++cur) {
        const int d = cur & 1;
        // P0 (0,0)
        asm volatile("s_waitcnt vmcnt(4)" ::: "memory");
        LD_A(a0, 0) LD_B(b0, 0)
        if (cur + 1 < NT) stageA(cur + 1, 1);
        MMA(0, 0, a0, b0)
        // P1 (0,1)
        LD_B(b1, 1)
        if (cur + 1 < NT) stageB(cur + 1, 1);
        MMA(0, 1, a0, b1)
        // P2 (1,0)
        LD_A(a1, 1)
        if (cur + 2 < NT) stageA(cur + 2, 0);
        MMA(1, 0, a1, b0)
        // P3 (1,1)
        asm volatile("s_waitcnt vmcnt(6)" ::: "memory");
        if (cur + 2 < NT) stageB(cur + 2, 0);
        MMA(1, 1, a1, b1)
    }
#undef LD_A
#undef LD_B
#undef MMA

#pragma unroll
    for (int fm = 0; fm < 8; ++fm)
#pragma unroll
        for (int fn = 0; fn < 4; ++fn)
#pragma unroll
            for (int r = 0; r < 4; ++r) {
                size_t row = (size_t)brow*256 + wm*128 + fm*16 + lhi*4 + r;
                size_t col = (size_t)bcol*256 + wn*64 + fn*16 + l16;
                if (OUT_BF16)
                    ((short*)Cout)[row * N + col] = f2bf(acc[fm][fn][r]);
                else
                    ((float*)Cout)[row * N + col] = acc[fm][fn][r];
            }
}

// ---------------- RoPE + split + V repack ----------------
// qkv bf16 [M1][NF]; freqs fp32 [SEQ][64][2]
// qb [B][NHEAD][SEQ][HD], kb [B][NKV][SEQ][HD]
// vg [B][NKV][SEQ/32][HD][32]   (per-32-key tile, V^T within tile: [d][key])
__global__ void rope_split_k(const short* __restrict__ qkv,
                             const float* __restrict__ freqs,
                             short* __restrict__ qb, short* __restrict__ kb,
                             short* __restrict__ vg) {
    int tid  = blockIdx.x * blockDim.x + threadIdx.x;   // one per 8 elems
    int colg = tid % (NF / 8);
    int row  = tid / (NF / 8);
    if (row >= M1) return;
    int b = row >> 11, s = row & 2047;
    int f = colg << 3;
    int h = f >> 7, d = f & 127;
    short8 v = *(const short8*)&qkv[(size_t)row * NF + f];
    if (h < NHEAD + NKV) {
        const float4 fa = *(const float4*)&freqs[(size_t)(s*64 + (d>>1)) * 2];
        const float4 fb = *(const float4*)&freqs[(size_t)(s*64 + (d>>1)) * 2 + 4];
        float fr[8] = {fa.x, fa.y, fa.z, fa.w, fb.x, fb.y, fb.z, fb.w};
        short8 o;
#pragma unroll
        for (int p = 0; p < 4; ++p) {
            float x0 = bf2f(v[2*p]), x1 = bf2f(v[2*p+1]);
            float c = fr[2*p], sn = fr[2*p+1];
            o[2*p]   = f2bf(x0 * c  - x1 * sn);
            o[2*p+1] = f2bf(x0 * sn + x1 * c);
        }
        if (h < NHEAD)
            *(short8*)&qb[((((size_t)b*NHEAD + h)*SEQ + s) << 7) + d] = o;
        else
            *(short8*)&kb[((((size_t)b*NKV + (h - NHEAD))*SEQ + s) << 7) + d] = o;
    } else {
        int kvh = h - NHEAD - NKV;
        size_t base = (((size_t)b*NKV + kvh) << 18) + (size_t)(s >> 5)*4096 + (s & 31);
#pragma unroll
        for (int j = 0; j < 8; ++j)
            vg[base + (size_t)(d + j) * 32] = v[j];
    }
}

// ---------------- flash attention (QBLK=128, KVB=32, dbuf, swapped QK) ----------------
__global__ __launch_bounds__(256, 3) void attn_k(const short* __restrict__ qb_,
                                                 const short* __restrict__ kb_,
                                                 const short* __restrict__ vg_,
                                                 short* __restrict__ yb) {
    __shared__ __align__(16) short Ks[2][32*128];   // [key][d], chunk-swizzled
    __shared__ __align__(16) short Vs[2][128*32];   // [d][key] per-tile, chunk-swizzled
    __shared__ __align__(16) short Pw[4][32*40];    // per-wave P [32 q][32 key + 8 pad]
    const int bid = blockIdx.x;
    const int qt = 15 - (bid >> 6);                 // heavy blocks dispatched first
    const int bh = bid & 63;
    const int b = bh >> 5, h = bh & 31, kv = h >> 2;
    const int t = threadIdx.x, lane = t & 63, w = t >> 6;
    const int l16 = lane & 15, lhi = lane >> 4;
    const short* Qp = qb_ + (((size_t)(b*NHEAD + h)*SEQ + qt*128 + w*32) << 7);
    const short* Kp = kb_ + (((size_t)(b*NKV + kv)*SEQ) << 7);
    const short* Vp = vg_ + (((size_t)(b*NKV + kv)*SEQ) << 7);
    short8 qf[2][4];
#pragma unroll
    for (int qq = 0; qq < 2; ++qq)
#pragma unroll
        for (int kk = 0; kk < 4; ++kk)
            qf[qq][kk] = *(const short8*)&Qp[(qq*16 + l16)*HD + kk*32 + lhi*8];
    f32x4 oacc[2][8] = {};
    float mrow[2] = {-1e30f, -1e30f};
    float lsum[2] = {0.f, 0.f};
    const int NT = (qt + 1) * 4;
    const int qmaxw = qt*128 + w*32 + 31;
    const float sc = 0.08838834764831845f;   // 1/sqrt(128)

    auto stage = [&](int kt, int buf) {
#pragma unroll
        for (int i = 0; i < 2; ++i) {          // K tile: 32 rows x 16 chunks
            int L = i*256 + t;
            int r = L >> 4, s = L & 15;
            int gs = (s & 8) | ((s & 7) ^ (r & 7));
            gload_lds16(Kp + (size_t)kt*4096 + r*128 + gs*8, &Ks[buf][L*8]);
        }
#pragma unroll
        for (int i = 0; i < 2; ++i) {          // V tile: 512 chunks, 8-chunk stripes
            int L = i*256 + t;
            int r8 = L >> 3, s3 = L & 7;
            int gs = s3 ^ (r8 & 7);
            gload_lds16(Vp + (size_t)kt*4096 + (r8*8 + gs)*8, &Vs[buf][L*8]);
        }
    };

    stage(0, 0);
    __syncthreads();
    int cur = 0;
    for (int kt = 0; kt < NT; ++kt) {
        if (kt + 1 < NT) stage(kt + 1, cur ^ 1);
        if (kt*32 <= qmaxw) {
            // S^T = K Q^T : row=key (kb*16+lhi*4+r), col=q (qq*16+l16)
            f32x4 sT[2][2] = {};
#pragma unroll
            for (int kk = 0; kk < 4; ++kk) {
                short8 kf[2];
#pragma unroll
                for (int kb2 = 0; kb2 < 2; ++kb2) {
                    int row = kb2*16 + l16;
                    int ch  = kk*4 + lhi;
                    int chs = (ch & 8) | ((ch & 7) ^ (row & 7));
                    kf[kb2] = *(const short8*)&Ks[cur][row*128 + chs*8];
                }
#pragma unroll
                for (int kb2 = 0; kb2 < 2; ++kb2)
#pragma unroll
                    for (int qq = 0; qq < 2; ++qq)
                        sT[kb2][qq] = __builtin_amdgcn_mfma_f32_16x16x32_bf16(kf[kb2], qf[qq][kk], sT[kb2][qq], 0, 0, 0);
            }
            // online softmax, per lane state for q = qq*16 + l16
#pragma unroll
            for (int qq = 0; qq < 2; ++qq) {
                int qg = qt*128 + w*32 + qq*16 + l16;
                float tmax = -1e30f;
#pragma unroll
                for (int kb2 = 0; kb2 < 2; ++kb2)
#pragma unroll
                    for (int r = 0; r < 4; ++r) {
                        int kg = kt*32 + kb2*16 + lhi*4 + r;
                        float sv = sT[kb2][qq][r] * sc;
                        sv = (kg > qg) ? -1e30f : sv;
                        sT[kb2][qq][r] = sv;
                        tmax = fmaxf(tmax, sv);
                    }
                tmax = fmaxf(tmax, __shfl_xor(tmax, 16, 64));
                tmax = fmaxf(tmax, __shfl_xor(tmax, 32, 64));
                float mn = fmaxf(mrow[qq], tmax);
                float alpha = __expf(mrow[qq] - mn);
                mrow[qq] = mn;
                float rsum = 0.f;
#pragma unroll
                for (int kb2 = 0; kb2 < 2; ++kb2) {
                    short4v pk;
#pragma unroll
                    for (int r = 0; r < 4; ++r) {
                        float p = __expf(sT[kb2][qq][r] - mn);
                        rsum += p;
                        pk[r] = f2bf(p);
                    }
                    *(short4v*)&Pw[w][(qq*16 + l16)*40 + kb2*16 + lhi*4] = pk;
                }
                rsum += __shfl_xor(rsum, 16, 64);
                rsum += __shfl_xor(rsum, 32, 64);
                lsum[qq] = lsum[qq]*alpha + rsum;
                // broadcast alpha to the lanes holding rows lhi*4+r of this q-block
                float a4[4];
#pragma unroll
                for (int r = 0; r < 4; ++r)
                    a4[r] = __shfl(alpha, (lane & 48) | (lhi*4 + r), 64);
#pragma unroll
                for (int n = 0; n < 8; ++n)
#pragma unroll
                    for (int r = 0; r < 4; ++r)
                        oacc[qq][n][r] *= a4[r];
            }
            // O += P V  (single k=32 MFMA per (qq,n))
            short8 pf[2];
#pragma unroll
            for (int qq = 0; qq < 2; ++qq)
                pf[qq] = *(const short8*)&Pw[w][(qq*16 + l16)*40 + lhi*8];
#pragma unroll
            for (int n = 0; n < 8; ++n) {
                int d   = n*16 + l16;
                int lch = d*4 + lhi;
                int phys = (lch & ~7) | ((lch & 7) ^ ((lch >> 3) & 7));
                short8 vf = *(const short8*)&Vs[cur][phys*8];
#pragma unroll
                for (int qq = 0; qq < 2; ++qq)
                    oacc[qq][n] = __builtin_amdgcn_mfma_f32_16x16x32_bf16(pf[qq], vf, oacc[qq][n], 0, 0, 0);
            }
        }
        __syncthreads();   // drains vmcnt: next buffer ready; protects cur buffer reuse
        cur ^= 1;
    }
#pragma unroll
    for (int qq = 0; qq < 2; ++qq) {
        float inv = 1.f / lsum[qq];
        float i4[4];
#pragma unroll
        for (int r = 0; r < 4; ++r)
            i4[r] = __shfl(inv, (lane & 48) | (lhi*4 + r), 64);
#pragma unroll
        for (int n = 0; n < 8; ++n)
#pragma unroll
            for (int r = 0; r < 4; ++r) {
                size_t row = (size_t)b*SEQ + qt*128 + w*32 + qq*16 + lhi*4 + r;
                yb[row*DIM + h*HD + n*16 + l16] = f2bf(oacc[qq][n][r] * i4[r]);
            }
    }
}

// ---------------- launch ----------------
extern "C" void kernel_launch(void* const* d_in, const int* in_sizes, int n_in,
                              void* d_out, int out_size, void* d_ws, size_t ws_size,
                              hipStream_t stream) {
    const float* x     = (const float*)d_in[0];
    const float* freqs = (const float*)d_in[1];
    // d_in[2] mask_cache (causal tril — hard-coded), d_in[3] input_pos (arange — unused)
    const float* wqkv  = (const float*)d_in[4];
    const float* wo    = (const float*)d_in[5];
    float* out = (float*)d_out;
    char* ws = (char*)d_ws;
    const size_t MB = 1024*1024;
    short* xb    = (short*)ws;              // 32MB  (later reused as yb)
    short* yb    = (short*)ws;
    short* wqkvb = (short*)(ws + 32*MB);    // 48MB  (later reused as wob)
    short* wob   = (short*)(ws + 32*MB);
    short* qkvb  = (short*)(ws + 80*MB);    // 48MB
    short* qb    = (short*)(ws + 128*MB);   // 32MB
    short* kb    = (short*)(ws + 160*MB);   // 8MB
    short* vg    = (short*)(ws + 168*MB);   // 8MB  (total 176MB)

    f2bf_k<<<(DIM*DIM/4 + 255)/256, 256, 0, stream>>>(x, xb, DIM*DIM/4);
    f2bf_k<<<(NF*DIM/4 + 255)/256, 256, 0, stream>>>(wqkv, wqkvb, NF*DIM/4);
    gemm256<1><<<(M1/256)*(NF/256), 512, 0, stream>>>(xb, wqkvb, qkvb, M1, NF, DIM);
    rope_split_k<<<(M1*(NF/8) + 255)/256, 256, 0, stream>>>(qkvb, freqs, qb, kb, vg);
    attn_k<<<BATCH*NHEAD*(SEQ/128), 256, 0, stream>>>(qb, kb, vg, yb);      // yb over xb: safe
    f2bf_k<<<(DIM*DIM/4 + 255)/256, 256, 0, stream>>>(wo, wob, DIM*DIM/4);  // wob over wqkvb: safe
    gemm256<0><<<(M1/256)*(DIM/256), 512, 0, stream>>>(yb, wob, out, M1, DIM, DIM);
}

// Round 5
// 554.702 us; speedup vs baseline: 1.5575x; 1.0035x over previous
//
#include <hip/hip_runtime.h>
#include <hip/hip_bf16.h>

#define DIM   4096
#define NHEAD 32
#define NKV   8
#define HD    128
#define BATCH 2
#define SEQ   2048
#define M1    (BATCH*SEQ)           // 4096 rows of x
#define NF    ((NHEAD+2*NKV)*HD)    // 6144 qkv features

typedef __attribute__((ext_vector_type(8))) short short8;
typedef __attribute__((ext_vector_type(4))) short short4v;
typedef __attribute__((ext_vector_type(4))) float f32x4;

__device__ __forceinline__ float bf2f(short s) {
    unsigned u = ((unsigned)(unsigned short)s) << 16;
    return __builtin_bit_cast(float, u);
}
__device__ __forceinline__ short f2bf(float f) {
    unsigned u = __builtin_bit_cast(unsigned, f);
    u = u + 0x7fffu + ((u >> 16) & 1u);   // RNE
    return (short)(u >> 16);
}

__device__ __forceinline__ void gload_lds16(const void* g, void* l) {
    __builtin_amdgcn_global_load_lds(
        (const __attribute__((address_space(1))) void*)g,
        (__attribute__((address_space(3))) void*)l, 16, 0, 0);
}

// ---------------- fp32 -> bf16 convert ----------------
__global__ void f2bf_k(const float* __restrict__ src, short* __restrict__ dst, int n4) {
    int i = blockIdx.x * blockDim.x + threadIdx.x;
    if (i >= n4) return;
    float4 v = ((const float4*)src)[i];
    short4v o;
    o[0] = f2bf(v.x); o[1] = f2bf(v.y); o[2] = f2bf(v.z); o[3] = f2bf(v.w);
    ((short4v*)dst)[i] = o;
}

// ============ 256x256 8-phase GEMM  C[M][N] = A[M][K] * Bm[N][K]^T ============
// 512 thr = 8 waves (2m x 4n); per-wave C = 128x64 = acc[8][4] f32x4.
// SOFTWARE-PIPELINED ds_reads (issued >=1 phase before consuming MFMA, so the
// LDS pipe drains under the MFMA cluster):
//   P0: MFMA(0,0,a0,b0)  reads b1(t)     stage A1(t+1)
//   P1: MFMA(0,1,a0,b1)  reads a1(t)     stage B1(t+1)   vmcnt(2) first
//   P2: MFMA(1,0,a1,b0)  reads a0(t+1)   stage A0(t+2)
//   P3: MFMA(1,1,a1,b1)  reads b0(t+1)   stage B0(t+2)   vmcnt(2) first
// Wait audit (2 loads per stage call/thread):
//   vmcnt(2)@P1(t): outstanding {A0(t+1)@P2(t-1), B0(t+1)@P3(t-1), A1(t+1)@P0(t)}
//     -> drains A0/B0(t+1) for reads at P2/P3(t) (1 barrier later). 
//   vmcnt(2)@P3(t): outstanding {A1(t+1)@P0(t), B1(t+1)@P1(t), A0(t+2)@P2(t)}
//     -> drains A1/B1(t+1) for reads at P1(t+1)/P0(t+1).
// Every ds_read is >=1 barrier after its certifying vmcnt (cross-wave safe);
// every staging overwrite is >=2 barriers after the slot's last read.
template<int OUT_BF16>
__global__ __launch_bounds__(512, 2) void gemm256(const short* __restrict__ A,
                                                  const short* __restrict__ Bm,
                                                  void* __restrict__ Cout,
                                                  int M, int N, int K) {
    __shared__ __align__(16) short As[2][2][128*64];   // 64KB [parity][quad]
    __shared__ __align__(16) short Bs[2][2][128*64];   // 64KB
    const int nbn = N >> 8;
    const int nwg = gridDim.x;
    const int cpx = nwg >> 3;
    const int swz = (blockIdx.x & 7) * cpx + (blockIdx.x >> 3);  // grids are %8==0
    const int brow = swz / nbn, bcol = swz % nbn;
    const int t = threadIdx.x, lane = t & 63, w = t >> 6;
    const int wm = w >> 2, wn = w & 3;
    const int l16 = lane & 15, lhi = lane >> 4, l7 = l16 & 7;
    const size_t abase = (size_t)brow * 256 * K;
    const size_t bbase = (size_t)bcol * 256 * K;
    const int sr = t >> 3;              // staging row-within-unit 0..63
    const int sc = t & 7;               // phys chunk
    const int scl = sc ^ (sr & 7);      // logical chunk this thread fetches
    f32x4 acc[8][4] = {};

    auto stageA = [&](int kt, int qm) {
#pragma unroll
        for (int i = 0; i < 2; ++i)
            gload_lds16(A + abase + (size_t)(i*128 + qm*64 + sr) * K + kt*64 + scl*8,
                        &As[kt & 1][qm][(i*64 + sr)*64 + sc*8]);
    };
    auto stageB = [&](int kt, int qn) {
#pragma unroll
        for (int i = 0; i < 2; ++i)
            gload_lds16(Bm + bbase + (size_t)((i*2 + (sr>>5))*64 + qn*32 + (sr & 31)) * K + kt*64 + scl*8,
                        &Bs[kt & 1][qn][(i*64 + sr)*64 + sc*8]);
    };

    const int NT = K >> 6;
    // prologue: A0(0) B0(0) A1(0) B1(0) A0(1) B0(1) = 12 loads/thread
    stageA(0, 0); stageB(0, 0); stageA(0, 1); stageB(0, 1);
    stageA(1, 0); stageB(1, 0);
    asm volatile("s_waitcnt vmcnt(4)" ::: "memory");   // tile0 fully landed
    __builtin_amdgcn_s_barrier();                      // cross-wave certify

    short8 a0[4][2], a1[4][2], b0[2][2], b1[2][2];

#define LD_A(dst, P, QM)                                                        \
    _Pragma("unroll") for (int mi = 0; mi < 4; ++mi)                            \
    _Pragma("unroll") for (int kk = 0; kk < 2; ++kk)                            \
        dst[mi][kk] = *(const short8*)&As[P][QM][(wm*64 + mi*16 + l16)*64 + (((kk*4 + lhi) ^ l7) * 8)];
#define LD_B(dst, P, QN)                                                        \
    _Pragma("unroll") for (int ni = 0; ni < 2; ++ni)                            \
    _Pragma("unroll") for (int kk = 0; kk < 2; ++kk)                            \
        dst[ni][kk] = *(const short8*)&Bs[P][QN][(wn*32 + ni*16 + l16)*64 + (((kk*4 + lhi) ^ l7) * 8)];
#define MMA(QM, QN, af, bf)                                                     \
    __builtin_amdgcn_s_barrier();                                               \
    __builtin_amdgcn_s_setprio(1);                                              \
    _Pragma("unroll") for (int kk = 0; kk < 2; ++kk)                            \
    _Pragma("unroll") for (int mi = 0; mi < 4; ++mi)                            \
    _Pragma("unroll") for (int ni = 0; ni < 2; ++ni)                            \
        acc[QM*4 + mi][QN*2 + ni] = __builtin_amdgcn_mfma_f32_16x16x32_bf16(    \
            af[mi][kk], bf[ni][kk], acc[QM*4 + mi][QN*2 + ni], 0, 0, 0);        \
    __builtin_amdgcn_s_setprio(0);                                              \
    __builtin_amdgcn_s_barrier();

    // pre-load tile-0 P0 fragments (certified by prologue vmcnt(4)+barrier)
    LD_A(a0, 0, 0)
    LD_B(b0, 0, 0)

    for (int cur = 0; cur < NT; ++cur) {
        const int d = cur & 1, dn = d ^ 1;
        // P0
        LD_B(b1, d, 1)
        if (cur + 1 < NT) stageA(cur + 1, 1);
        MMA(0, 0, a0, b0)
        // P1
        asm volatile("s_waitcnt vmcnt(2)" ::: "memory");
        LD_A(a1, d, 1)
        if (cur + 1 < NT) stageB(cur + 1, 1);
        MMA(0, 1, a0, b1)
        // P2  (a0 dead after P1 -> refill with next tile's A0)
        LD_A(a0, dn, 0)
        if (cur + 2 < NT) stageA(cur + 2, 0);
        MMA(1, 0, a1, b0)
        // P3  (b0 dead after P2 -> refill with next tile's B0)
        asm volatile("s_waitcnt vmcnt(2)" ::: "memory");
        LD_B(b0, dn, 0)
        if (cur + 2 < NT) stageB(cur + 2, 0);
        MMA(1, 1, a1, b1)
    }
#undef LD_A
#undef LD_B
#undef MMA

#pragma unroll
    for (int fm = 0; fm < 8; ++fm)
#pragma unroll
        for (int fn = 0; fn < 4; ++fn)
#pragma unroll
            for (int r = 0; r < 4; ++r) {
                size_t row = (size_t)brow*256 + wm*128 + fm*16 + lhi*4 + r;
                size_t col = (size_t)bcol*256 + wn*64 + fn*16 + l16;
                if (OUT_BF16)
                    ((short*)Cout)[row * N + col] = f2bf(acc[fm][fn][r]);
                else
                    ((float*)Cout)[row * N + col] = acc[fm][fn][r];
            }
}

// ---------------- RoPE + split + V repack ----------------
// qkv bf16 [M1][NF]; freqs fp32 [SEQ][64][2]
// qb [B][NHEAD][SEQ][HD], kb [B][NKV][SEQ][HD]
// vg [B][NKV][SEQ/32][HD][32]   (per-32-key tile, V^T within tile: [d][key])
__global__ void rope_split_k(const short* __restrict__ qkv,
                             const float* __restrict__ freqs,
                             short* __restrict__ qb, short* __restrict__ kb,
                             short* __restrict__ vg) {
    int tid  = blockIdx.x * blockDim.x + threadIdx.x;   // one per 8 elems
    int colg = tid % (NF / 8);
    int row  = tid / (NF / 8);
    if (row >= M1) return;
    int b = row >> 11, s = row & 2047;
    int f = colg << 3;
    int h = f >> 7, d = f & 127;
    short8 v = *(const short8*)&qkv[(size_t)row * NF + f];
    if (h < NHEAD + NKV) {
        const float4 fa = *(const float4*)&freqs[(size_t)(s*64 + (d>>1)) * 2];
        const float4 fb = *(const float4*)&freqs[(size_t)(s*64 + (d>>1)) * 2 + 4];
        float fr[8] = {fa.x, fa.y, fa.z, fa.w, fb.x, fb.y, fb.z, fb.w};
        short8 o;
#pragma unroll
        for (int p = 0; p < 4; ++p) {
            float x0 = bf2f(v[2*p]), x1 = bf2f(v[2*p+1]);
            float c = fr[2*p], sn = fr[2*p+1];
            o[2*p]   = f2bf(x0 * c  - x1 * sn);
            o[2*p+1] = f2bf(x0 * sn + x1 * c);
        }
        if (h < NHEAD)
            *(short8*)&qb[((((size_t)b*NHEAD + h)*SEQ + s) << 7) + d] = o;
        else
            *(short8*)&kb[((((size_t)b*NKV + (h - NHEAD))*SEQ + s) << 7) + d] = o;
    } else {
        int kvh = h - NHEAD - NKV;
        size_t base = (((size_t)b*NKV + kvh) << 18) + (size_t)(s >> 5)*4096 + (s & 31);
#pragma unroll
        for (int j = 0; j < 8; ++j)
            vg[base + (size_t)(d + j) * 32] = v[j];
    }
}

// ---------------- flash attention (QBLK=128, KVB=32, dbuf, swapped QK) ----------------
__global__ __launch_bounds__(256, 3) void attn_k(const short* __restrict__ qb_,
                                                 const short* __restrict__ kb_,
                                                 const short* __restrict__ vg_,
                                                 short* __restrict__ yb) {
    __shared__ __align__(16) short Ks[2][32*128];   // [key][d], chunk-swizzled
    __shared__ __align__(16) short Vs[2][128*32];   // [d][key] per-tile, chunk-swizzled
    __shared__ __align__(16) short Pw[4][32*40];    // per-wave P [32 q][32 key + 8 pad]
    const int bid = blockIdx.x;
    const int qt = 15 - (bid >> 6);                 // heavy blocks dispatched first
    const int bh = bid & 63;
    const int b = bh >> 5, h = bh & 31, kv = h >> 2;
    const int t = threadIdx.x, lane = t & 63, w = t >> 6;
    const int l16 = lane & 15, lhi = lane >> 4;
    const short* Qp = qb_ + (((size_t)(b*NHEAD + h)*SEQ + qt*128 + w*32) << 7);
    const short* Kp = kb_ + (((size_t)(b*NKV + kv)*SEQ) << 7);
    const short* Vp = vg_ + (((size_t)(b*NKV + kv)*SEQ) << 7);
    short8 qf[2][4];
#pragma unroll
    for (int qq = 0; qq < 2; ++qq)
#pragma unroll
        for (int kk = 0; kk < 4; ++kk)
            qf[qq][kk] = *(const short8*)&Qp[(qq*16 + l16)*HD + kk*32 + lhi*8];
    f32x4 oacc[2][8] = {};
    float mrow[2] = {-1e30f, -1e30f};
    float lsum[2] = {0.f, 0.f};
    const int NT = (qt + 1) * 4;
    const int qmaxw = qt*128 + w*32 + 31;
    const float sc = 0.08838834764831845f;   // 1/sqrt(128)

    auto stage = [&](int kt, int buf) {
#pragma unroll
        for (int i = 0; i < 2; ++i) {          // K tile: 32 rows x 16 chunks
            int L = i*256 + t;
            int r = L >> 4, s = L & 15;
            int gs = (s & 8) | ((s & 7) ^ (r & 7));
            gload_lds16(Kp + (size_t)kt*4096 + r*128 + gs*8, &Ks[buf][L*8]);
        }
#pragma unroll
        for (int i = 0; i < 2; ++i) {          // V tile: 512 chunks, 8-chunk stripes
            int L = i*256 + t;
            int r8 = L >> 3, s3 = L & 7;
            int gs = s3 ^ (r8 & 7);
            gload_lds16(Vp + (size_t)kt*4096 + (r8*8 + gs)*8, &Vs[buf][L*8]);
        }
    };

    stage(0, 0);
    __syncthreads();
    int cur = 0;
    for (int kt = 0; kt < NT; ++kt) {
        if (kt + 1 < NT) stage(kt + 1, cur ^ 1);
        if (kt*32 <= qmaxw) {
            // S^T = K Q^T : row=key (kb*16+lhi*4+r), col=q (qq*16+l16)
            f32x4 sT[2][2] = {};
#pragma unroll
            for (int kk = 0; kk < 4; ++kk) {
                short8 kf[2];
#pragma unroll
                for (int kb2 = 0; kb2 < 2; ++kb2) {
                    int row = kb2*16 + l16;
                    int ch  = kk*4 + lhi;
                    int chs = (ch & 8) | ((ch & 7) ^ (row & 7));
                    kf[kb2] = *(const short8*)&Ks[cur][row*128 + chs*8];
                }
#pragma unroll
                for (int kb2 = 0; kb2 < 2; ++kb2)
#pragma unroll
                    for (int qq = 0; qq < 2; ++qq)
                        sT[kb2][qq] = __builtin_amdgcn_mfma_f32_16x16x32_bf16(kf[kb2], qf[qq][kk], sT[kb2][qq], 0, 0, 0);
            }
            // online softmax, per lane state for q = qq*16 + l16
#pragma unroll
            for (int qq = 0; qq < 2; ++qq) {
                int qg = qt*128 + w*32 + qq*16 + l16;
                float tmax = -1e30f;
#pragma unroll
                for (int kb2 = 0; kb2 < 2; ++kb2)
#pragma unroll
                    for (int r = 0; r < 4; ++r) {
                        int kg = kt*32 + kb2*16 + lhi*4 + r;
                        float sv = sT[kb2][qq][r] * sc;
                        sv = (kg > qg) ? -1e30f : sv;
                        sT[kb2][qq][r] = sv;
                        tmax = fmaxf(tmax, sv);
                    }
                tmax = fmaxf(tmax, __shfl_xor(tmax, 16, 64));
                tmax = fmaxf(tmax, __shfl_xor(tmax, 32, 64));
                float mn = fmaxf(mrow[qq], tmax);
                float alpha = __expf(mrow[qq] - mn);
                mrow[qq] = mn;
                float rsum = 0.f;
#pragma unroll
                for (int kb2 = 0; kb2 < 2; ++kb2) {
                    short4v pk;
#pragma unroll
                    for (int r = 0; r < 4; ++r) {
                        float p = __expf(sT[kb2][qq][r] - mn);
                        rsum += p;
                        pk[r] = f2bf(p);
                    }
                    *(short4v*)&Pw[w][(qq*16 + l16)*40 + kb2*16 + lhi*4] = pk;
                }
                rsum += __shfl_xor(rsum, 16, 64);
                rsum += __shfl_xor(rsum, 32, 64);
                lsum[qq] = lsum[qq]*alpha + rsum;
                // broadcast alpha to the lanes holding rows lhi*4+r of this q-block
                float a4[4];
#pragma unroll
                for (int r = 0; r < 4; ++r)
                    a4[r] = __shfl(alpha, (lane & 48) | (lhi*4 + r), 64);
#pragma unroll
                for (int n = 0; n < 8; ++n)
#pragma unroll
                    for (int r = 0; r < 4; ++r)
                        oacc[qq][n][r] *= a4[r];
            }
            // O += P V  (single k=32 MFMA per (qq,n))
            short8 pf[2];
#pragma unroll
            for (int qq = 0; qq < 2; ++qq)
                pf[qq] = *(const short8*)&Pw[w][(qq*16 + l16)*40 + lhi*8];
#pragma unroll
            for (int n = 0; n < 8; ++n) {
                int d   = n*16 + l16;
                int lch = d*4 + lhi;
                int phys = (lch & ~7) | ((lch & 7) ^ ((lch >> 3) & 7));
                short8 vf = *(const short8*)&Vs[cur][phys*8];
#pragma unroll
                for (int qq = 0; qq < 2; ++qq)
                    oacc[qq][n] = __builtin_amdgcn_mfma_f32_16x16x32_bf16(pf[qq], vf, oacc[qq][n], 0, 0, 0);
            }
        }
        __syncthreads();   // drains vmcnt: next buffer ready; protects cur buffer reuse
        cur ^= 1;
    }
#pragma unroll
    for (int qq = 0; qq < 2; ++qq) {
        float inv = 1.f / lsum[qq];
        float i4[4];
#pragma unroll
        for (int r = 0; r < 4; ++r)
            i4[r] = __shfl(inv, (lane & 48) | (lhi*4 + r), 64);
#pragma unroll
        for (int n = 0; n < 8; ++n)
#pragma unroll
            for (int r = 0; r < 4; ++r) {
                size_t row = (size_t)b*SEQ + qt*128 + w*32 + qq*16 + lhi*4 + r;
                yb[row*DIM + h*HD + n*16 + l16] = f2bf(oacc[qq][n][r] * i4[r]);
            }
    }
}

// ---------------- launch ----------------
extern "C" void kernel_launch(void* const* d_in, const int* in_sizes, int n_in,
                              void* d_out, int out_size, void* d_ws, size_t ws_size,
                              hipStream_t stream) {
    const float* x     = (const float*)d_in[0];
    const float* freqs = (const float*)d_in[1];
    // d_in[2] mask_cache (causal tril — hard-coded), d_in[3] input_pos (arange — unused)
    const float* wqkv  = (const float*)d_in[4];
    const float* wo    = (const float*)d_in[5];
    float* out = (float*)d_out;
    char* ws = (char*)d_ws;
    const size_t MB = 1024*1024;
    short* xb    = (short*)ws;              // 32MB  (later reused as yb)
    short* yb    = (short*)ws;
    short* wqkvb = (short*)(ws + 32*MB);    // 48MB  (later reused as wob)
    short* wob   = (short*)(ws + 32*MB);
    short* qkvb  = (short*)(ws + 80*MB);    // 48MB
    short* qb    = (short*)(ws + 128*MB);   // 32MB
    short* kb    = (short*)(ws + 160*MB);   // 8MB
    short* vg    = (short*)(ws + 168*MB);   // 8MB  (total 176MB)

    f2bf_k<<<(DIM*DIM/4 + 255)/256, 256, 0, stream>>>(x, xb, DIM*DIM/4);
    f2bf_k<<<(NF*DIM/4 + 255)/256, 256, 0, stream>>>(wqkv, wqkvb, NF*DIM/4);
    gemm256<1><<<(M1/256)*(NF/256), 512, 0, stream>>>(xb, wqkvb, qkvb, M1, NF, DIM);
    rope_split_k<<<(M1*(NF/8) + 255)/256, 256, 0, stream>>>(qkvb, freqs, qb, kb, vg);
    attn_k<<<BATCH*NHEAD*(SEQ/128), 256, 0, stream>>>(qb, kb, vg, yb);      // yb over xb: safe
    f2bf_k<<<(DIM*DIM/4 + 255)/256, 256, 0, stream>>>(wo, wob, DIM*DIM/4);  // wob over wqkvb: safe
    gemm256<0><<<(M1/256)*(DIM/256), 512, 0, stream>>>(yb, wob, out, M1, DIM, DIM);
}